// Round 1
// 322.278 us; speedup vs baseline: 1.1325x; 1.1325x over previous
//
#include <hip/hip_runtime.h>

#define EPS 1e-5f
#define BSHIFT 8
#define BSIZE  256
#define NBMAX  512   // covers N up to 131072 with 256-node buckets
#define PCHUNK 8192  // edges per k_bpart block (LDS-staged multisplit)

__device__ __forceinline__ unsigned short f2bf(float f) {
    unsigned u = __float_as_uint(f);
    u += 0x7FFFu + ((u >> 16) & 1u);     // round-to-nearest-even
    return (unsigned short)(u >> 16);
}
__device__ __forceinline__ float bf2f(unsigned short s) {
    return __uint_as_float(((unsigned)s) << 16);
}
__device__ __forceinline__ void acc8(float* acc, uint4 v) {
    acc[0] += bf2f((unsigned short)(v.x & 0xFFFFu)); acc[1] += bf2f((unsigned short)(v.x >> 16));
    acc[2] += bf2f((unsigned short)(v.y & 0xFFFFu)); acc[3] += bf2f((unsigned short)(v.y >> 16));
    acc[4] += bf2f((unsigned short)(v.z & 0xFFFFu)); acc[5] += bf2f((unsigned short)(v.z >> 16));
    acc[6] += bf2f((unsigned short)(v.w & 0xFFFFu)); acc[7] += bf2f((unsigned short)(v.w >> 16));
}

__global__ __launch_bounds__(512) void k_zero(unsigned* ghist, int NB) {
    int t = threadIdx.x;
    if (t < NB) ghist[t] = 0u;
}

// bucket histogram: LDS-aggregated (4096 edges/block)
__global__ __launch_bounds__(256) void k_bhist(const int* __restrict__ ei,
                                               unsigned* __restrict__ ghist, int E, int NB) {
    __shared__ unsigned sh[NBMAX];
    int t = threadIdx.x;
    for (int i = t; i < NB; i += 256) sh[i] = 0u;
    __syncthreads();
    const int4* dst4 = (const int4*)(ei + E);
    int E4 = E >> 2;
    int base4 = blockIdx.x * 1024;
#pragma unroll
    for (int i = 0; i < 4; i++) {
        int idx = base4 + i * 256 + t;
        if (idx < E4) {
            int4 d = dst4[idx];
            atomicAdd(&sh[d.x >> BSHIFT], 1u);
            atomicAdd(&sh[d.y >> BSHIFT], 1u);
            atomicAdd(&sh[d.z >> BSHIFT], 1u);
            atomicAdd(&sh[d.w >> BSHIFT], 1u);
        }
    }
    __syncthreads();
    for (int i = t; i < NB; i += 256) if (sh[i]) atomicAdd(&ghist[i], sh[i]);
}

// exclusive scan of ghist[NB] (NB <= 512) -> base, cursor; sentinels
__global__ __launch_bounds__(512) void k_bscan(const unsigned* __restrict__ ghist,
                                               unsigned* __restrict__ base,
                                               unsigned* __restrict__ cursor,
                                               unsigned* __restrict__ nstart,
                                               int NB, int N, int E) {
    __shared__ unsigned sh[512];
    int t = threadIdx.x;
    unsigned v = (t < NB) ? ghist[t] : 0u;
    sh[t] = v;
    __syncthreads();
    for (int off = 1; off < 512; off <<= 1) {
        unsigned a = (t >= off) ? sh[t - off] : 0u;
        __syncthreads();
        sh[t] += a;
        __syncthreads();
    }
    if (t < NB) { unsigned ex = sh[t] - v; base[t] = ex; cursor[t] = ex; }
    if (t == 0) { base[NB] = (unsigned)E; nstart[N] = (unsigned)E; }
}

// partition edges into bucket streams; packed u32 = src | (dst&255)<<17.
// LDS-staged multisplit: reorder the 8192-edge chunk into bucket-sorted order
// in LDS, then write out so consecutive LDS positions -> consecutive global
// addresses within each bucket run (kills the 4B-scattered-store write
// amplification that made the old version TCC-request-bound).
__global__ __launch_bounds__(512) void k_bpart(const int* __restrict__ ei,
                                               unsigned* __restrict__ cursor,
                                               unsigned* __restrict__ sorted, int E, int NB) {
    __shared__ unsigned cnt[NBMAX];          // per-bucket count, then rank counter
    __shared__ unsigned lbase[NBMAX];        // reserved global base per bucket
    __shared__ unsigned loff[NBMAX + 1];     // local exclusive scan
    __shared__ unsigned sh[512];             // scan temp
    __shared__ unsigned stage[PCHUNK];       // 32KB bucket-sorted staging
    __shared__ unsigned short bkt[PCHUNK];   // 16KB bucket id per staged position
    int t = threadIdx.x;
    for (int i = t; i < NB; i += 512) cnt[i] = 0u;
    __syncthreads();
    const int4* src4 = (const int4*)ei;
    const int4* dst4 = (const int4*)(ei + E);
    int E4 = E >> 2;
    int base4 = blockIdx.x * (PCHUNK / 4);
    // phase A: per-block histogram
#pragma unroll
    for (int i = 0; i < PCHUNK / 4 / 512; i++) {
        int idx = base4 + i * 512 + t;
        if (idx < E4) {
            int4 d = dst4[idx];
            atomicAdd(&cnt[d.x >> BSHIFT], 1u);
            atomicAdd(&cnt[d.y >> BSHIFT], 1u);
            atomicAdd(&cnt[d.z >> BSHIFT], 1u);
            atomicAdd(&cnt[d.w >> BSHIFT], 1u);
        }
    }
    __syncthreads();
    // phase B: reserve global space per bucket + local exclusive scan
    unsigned v = (t < NB) ? cnt[t] : 0u;
    sh[t] = v;
    if (t < NB) lbase[t] = v ? atomicAdd(&cursor[t], v) : 0u;
    __syncthreads();
    for (int off = 1; off < 512; off <<= 1) {
        unsigned a = (t >= off) ? sh[t - off] : 0u;
        __syncthreads();
        sh[t] += a;
        __syncthreads();
    }
    if (t < NB) { loff[t] = sh[t] - v; cnt[t] = 0u; }   // cnt reused as rank ctr
    if (t == NB - 1) loff[NB] = sh[t];                  // total staged count
    __syncthreads();
    // phase C1: fill bucket-of-position (writes bkt[], disjoint from stage[])
    for (int b = t; b < NB; b += 512) {
        unsigned s = loff[b], e2 = loff[b + 1];
        for (unsigned j = s; j < e2; j++) bkt[j] = (unsigned short)b;
    }
    // phase C2: scatter edges into stage in bucket-sorted order
#pragma unroll
    for (int i = 0; i < PCHUNK / 4 / 512; i++) {
        int idx = base4 + i * 512 + t;
        if (idx < E4) {
            int4 s = src4[idx];
            int4 d = dst4[idx];
            int b; unsigned r;
            b = d.x >> BSHIFT; r = atomicAdd(&cnt[b], 1u);
            stage[loff[b] + r] = (unsigned)s.x | ((unsigned)(d.x & (BSIZE - 1)) << 17);
            b = d.y >> BSHIFT; r = atomicAdd(&cnt[b], 1u);
            stage[loff[b] + r] = (unsigned)s.y | ((unsigned)(d.y & (BSIZE - 1)) << 17);
            b = d.z >> BSHIFT; r = atomicAdd(&cnt[b], 1u);
            stage[loff[b] + r] = (unsigned)s.z | ((unsigned)(d.z & (BSIZE - 1)) << 17);
            b = d.w >> BSHIFT; r = atomicAdd(&cnt[b], 1u);
            stage[loff[b] + r] = (unsigned)s.w | ((unsigned)(d.w & (BSIZE - 1)) << 17);
        }
    }
    __syncthreads();
    // phase D: run-contiguous writeout (consecutive i -> consecutive global
    // addresses within each bucket run of ~21 entries)
    unsigned total = loff[NB];
    for (unsigned i = t; i < total; i += 512) {
        unsigned b = bkt[i];
        sorted[lbase[b] + (i - loff[b])] = stage[i];
    }
}

// per-bucket degree count + block scan -> nstart (global CSR row starts) + dinv
__global__ __launch_bounds__(256) void k_bdeg2(const unsigned* __restrict__ base,
                                               const unsigned* __restrict__ sorted,
                                               unsigned* __restrict__ nstart,
                                               float* __restrict__ dinv, int N) {
    __shared__ unsigned deg[BSIZE];
    int b = blockIdx.x, t = threadIdx.x;
    deg[t] = 0u;
    __syncthreads();
    unsigned s0 = base[b], s1 = base[b + 1];
    for (unsigned j = s0 + t; j < s1; j += 256)
        atomicAdd(&deg[sorted[j] >> 17], 1u);
    __syncthreads();
    unsigned d0 = deg[t];
    int lane = t & 63, wid = t >> 6;
    unsigned inc = d0;
    for (int off = 1; off < 64; off <<= 1) {
        unsigned u = __shfl_up(inc, off, 64);
        if (lane >= off) inc += u;
    }
    __shared__ unsigned wsum[4];
    if (lane == 63) wsum[wid] = inc;
    __syncthreads();
    unsigned wbase = 0;
    for (int w = 0; w < wid; w++) wbase += wsum[w];
    unsigned excl = wbase + inc - d0;
    int node = (b << BSHIFT) + t;
    if (node < N) {
        nstart[node] = s0 + excl;
        dinv[node] = rsqrtf((float)(d0 + 1u));   // +1 = self-loop
    }
}

// per-bucket counting-sort placement -> sorted2[j] = src, dst-sorted CSR order
__global__ __launch_bounds__(256) void k_bsort(const unsigned* __restrict__ base,
                                               const unsigned* __restrict__ nstart,
                                               const unsigned* __restrict__ sorted,
                                               unsigned* __restrict__ sorted2, int N) {
    __shared__ unsigned cur[BSIZE];
    int b = blockIdx.x, t = threadIdx.x;
    int node = (b << BSHIFT) + t;
    cur[t] = (node < N) ? nstart[node] : 0u;
    __syncthreads();
    unsigned s0 = base[b], s1 = base[b + 1];
    for (unsigned j = s0 + t; j < s1; j += 256) {
        unsigned u = sorted[j];
        unsigned pos = atomicAdd(&cur[u >> 17], 1u);
        sorted2[pos] = u & 0x1FFFFu;
    }
}

// hs[n][r] = (sum_k x[n][k]*W[r][k]) * dinv[n], stored bf16.
__global__ __launch_bounds__(256) void k_gemm(const float* __restrict__ x,
                                              const float* __restrict__ W,
                                              const float* __restrict__ dinv,
                                              unsigned short* __restrict__ hs, int N) {
    __shared__ float ws[16 * 256];       // W fp32, 16KB
    int t = threadIdx.x;
    for (int i = t; i < 1024; i += 256) ((float4*)ws)[i] = ((const float4*)W)[i];
    __syncthreads();
    int node = blockIdx.x * 256 + t;
    if (node >= N) return;
    const float4* xr = (const float4*)(x + (size_t)node * 256);
    float acc[16];
#pragma unroll
    for (int r = 0; r < 16; r++) acc[r] = 0.f;
#pragma unroll 4
    for (int k = 0; k < 64; k++) {
        float4 a = xr[k];
#pragma unroll
        for (int r = 0; r < 16; r++) {
            float4 w = ((const float4*)ws)[r * 64 + k];   // wave-broadcast LDS read
            acc[r] += a.x * w.x + a.y * w.y + a.z * w.z + a.w * w.w;
        }
    }
    float dv = dinv[node];
    unsigned pk[8];
#pragma unroll
    for (int i = 0; i < 8; i++)
        pk[i] = (unsigned)f2bf(acc[2 * i] * dv) | ((unsigned)f2bf(acc[2 * i + 1] * dv) << 16);
    uint4* dst = (uint4*)(hs + (size_t)node * 16);
    dst[0] = make_uint4(pk[0], pk[1], pk[2], pk[3]);
    dst[1] = make_uint4(pk[4], pk[5], pk[6], pk[7]);
}

// wide-load pull aggregation: 16 lanes per node; lane r handles rows j+(r>>1)
// and channel-half (r&1), loading full uint4 (8 bf16) per row.
// LN-stats partial -> PLAIN float2 store per block (no same-address atomics).
__global__ __launch_bounds__(256) void k_agg3(const unsigned* __restrict__ nstart,
                                              const unsigned* __restrict__ sorted2,
                                              const unsigned short* __restrict__ hs,
                                              const float* __restrict__ dinv,
                                              const float* __restrict__ bias,
                                              float* __restrict__ agg,
                                              float2* __restrict__ part, int N) {
    int t = threadIdx.x;
    int g = t >> 4, r = t & 15;
    int d = blockIdx.x * 16 + g;
    int sub = r >> 1;                    // row offset 0..7
    int half = r & 1;                    // channel half
    float acc[8];
#pragma unroll
    for (int c = 0; c < 8; c++) acc[c] = 0.f;
    unsigned s0 = 0, s1 = 0;
    if (d < N) { s0 = nstart[d]; s1 = nstart[d + 1]; }
    for (unsigned j = s0; j < s1; j += 16) {
        unsigned row0 = j + sub, row1 = j + 8 + sub;
        bool p0 = row0 < s1, p1 = row1 < s1;
        unsigned i0 = 0, i1 = 0;
        if (p0) i0 = sorted2[row0];
        if (p1) i1 = sorted2[row1];
        uint4 v0, v1;
        if (p0) v0 = ((const uint4*)(hs + (size_t)i0 * 16))[half];
        if (p1) v1 = ((const uint4*)(hs + (size_t)i1 * 16))[half];
        if (p0) acc8(acc, v0);
        if (p1) acc8(acc, v1);
    }
    // reduce across stride-2 lanes (rows residues); lanes 0/1 of each group get totals.
#pragma unroll
    for (int off = 2; off <= 8; off <<= 1) {
#pragma unroll
        for (int c = 0; c < 8; c++) acc[c] += __shfl_down(acc[c], off, 64);
    }
    float s = 0.f, q = 0.f;
    if (d < N && r < 2) {
        float dd = dinv[d];
        uint4 hv = ((const uint4*)(hs + (size_t)d * 16))[half];
        float self[8];
        self[0] = bf2f((unsigned short)(hv.x & 0xFFFFu)); self[1] = bf2f((unsigned short)(hv.x >> 16));
        self[2] = bf2f((unsigned short)(hv.y & 0xFFFFu)); self[3] = bf2f((unsigned short)(hv.y >> 16));
        self[4] = bf2f((unsigned short)(hv.z & 0xFFFFu)); self[5] = bf2f((unsigned short)(hv.z >> 16));
        self[6] = bf2f((unsigned short)(hv.w & 0xFFFFu)); self[7] = bf2f((unsigned short)(hv.w >> 16));
        float o[8];
#pragma unroll
        for (int c = 0; c < 8; c++) o[c] = (acc[c] + self[c]) * dd;
        float* an = agg + (size_t)d * 16 + half * 8;
        *(float4*)(an)     = make_float4(o[0], o[1], o[2], o[3]);
        *(float4*)(an + 4) = make_float4(o[4], o[5], o[6], o[7]);
        const float* bp = bias + half * 8;
        float4 b0 = *(const float4*)bp, b1 = *(const float4*)(bp + 4);
        float a0 = o[0] + b0.x, a1 = o[1] + b0.y, a2 = o[2] + b0.z, a3 = o[3] + b0.w;
        float a4 = o[4] + b1.x, a5 = o[5] + b1.y, a6 = o[6] + b1.z, a7 = o[7] + b1.w;
        s = (a0 + a1) + (a2 + a3) + (a4 + a5) + (a6 + a7);
        q = a0 * a0 + a1 * a1 + a2 * a2 + a3 * a3 + a4 * a4 + a5 * a5 + a6 * a6 + a7 * a7;
    }
    for (int off = 32; off > 0; off >>= 1) {
        s += __shfl_down(s, off, 64);
        q += __shfl_down(q, off, 64);
    }
    __shared__ float ss[4], qq[4];
    int lane = t & 63, wid = t >> 6;
    if (lane == 0) { ss[wid] = s; qq[wid] = q; }
    __syncthreads();
    if (t == 0)
        part[blockIdx.x] = make_float2(ss[0] + ss[1] + ss[2] + ss[3],
                                       qq[0] + qq[1] + qq[2] + qq[3]);
}

// single-block reduction of per-block partials -> scal (plain stores, no atomics)
__global__ __launch_bounds__(256) void k_statsred(const float2* __restrict__ part,
                                                  float* __restrict__ scal, int M) {
    int t = threadIdx.x;
    float s = 0.f, q = 0.f;
    for (int i = t; i < M; i += 256) {
        float2 v = part[i];
        s += v.x; q += v.y;
    }
    for (int off = 32; off > 0; off >>= 1) {
        s += __shfl_down(s, off, 64);
        q += __shfl_down(q, off, 64);
    }
    __shared__ float ss[4], qq[4];
    int lane = t & 63, wid = t >> 6;
    if (lane == 0) { ss[wid] = s; qq[wid] = q; }
    __syncthreads();
    if (t == 0) {
        scal[0] = ss[0] + ss[1] + ss[2] + ss[3];
        scal[1] = qq[0] + qq[1] + qq[2] + qq[3];
    }
}

// per batch row: LN + PReLU on 16 channels, then x trans[16,128] -> out[B,128]
__global__ __launch_bounds__(256) void k_final(const float* __restrict__ agg,
                                               const int* __restrict__ batch,
                                               const float* __restrict__ trans,
                                               const float* __restrict__ bias,
                                               const float* __restrict__ ln_w,
                                               const float* __restrict__ ln_b,
                                               const float* __restrict__ prelu_a,
                                               const float* __restrict__ scal,
                                               float* __restrict__ out, int B, float invCnt) {
    __shared__ float tl[16 * 128];
    __shared__ float hh[2 * 16];
    const int tid = threadIdx.x;
    for (int i = tid; i < 2048; i += 256) tl[i] = trans[i];
    float mean = scal[0] * invCnt;
    float var  = scal[1] * invCnt - mean * mean;
    float inv  = rsqrtf(var + EPS);
    int row0 = blockIdx.x * 2;
    if (tid < 32) {
        int lr = tid >> 4, r = tid & 15;
        int row = row0 + lr;
        if (row < B) {
            int node = batch[row];
            float v = agg[(size_t)node * 16 + r] + bias[r];
            v = (v - mean) * inv * ln_w[r] + ln_b[r];
            float a = prelu_a[0];
            v = v >= 0.f ? v : a * v;
            hh[lr * 16 + r] = v;
        }
    }
    __syncthreads();
    int lr = tid >> 7, d = tid & 127;
    int row = row0 + lr;
    if (row >= B) return;
    const float* hrow = hh + lr * 16;
    float acc = 0.f;
#pragma unroll
    for (int r = 0; r < 16; r++) acc += hrow[r] * tl[r * 128 + d];
    out[(size_t)row * 128 + d] = acc;
}

extern "C" void kernel_launch(void* const* d_in, const int* in_sizes, int n_in,
                              void* d_out, int out_size, void* d_ws, size_t ws_size,
                              hipStream_t stream) {
    const float* x       = (const float*)d_in[0];
    const int*   ei      = (const int*)d_in[1];
    const float* trans   = (const float*)d_in[2];
    const int*   batch   = (const int*)d_in[3];
    const float* W       = (const float*)d_in[4];
    const float* bias    = (const float*)d_in[5];
    const float* ln_w    = (const float*)d_in[6];
    const float* ln_b    = (const float*)d_in[7];
    const float* prelu_a = (const float*)d_in[8];
    float* out = (float*)d_out;

    const int N = in_sizes[0] / 256;   // 100000
    const int E = in_sizes[1] / 2;     // 3200000
    const int B = in_sizes[3];         // 16384
    const int NB = (N + BSIZE - 1) >> BSHIFT;   // 391
    const int NBLK = (N + 15) / 16;    // 6250 agg blocks

    char* p = (char*)d_ws;
    unsigned short* hs = (unsigned short*)p;  p += (size_t)N * 16 * 2;    // 3.2MB bf16
    float*    agg     = (float*)p;     p += (size_t)N * 16 * 4;           // 6.4MB
    unsigned* sorted  = (unsigned*)p;  p += (size_t)E * 4;                // 12.8MB
    unsigned* sorted2 = (unsigned*)p;  p += (size_t)E * 4;                // 12.8MB
    float*    dinv    = (float*)p;     p += (size_t)N * 4;
    unsigned* nstart  = (unsigned*)p;  p += (size_t)(N + 1) * 4;
    unsigned* ghist   = (unsigned*)p;  p += NBMAX * 4;
    unsigned* base    = (unsigned*)p;  p += (NBMAX + 1) * 4;
    unsigned* cursor  = (unsigned*)p;  p += NBMAX * 4;
    float*    scal    = (float*)p;     p += 2 * 4;
    p = (char*)(((size_t)p + 7) & ~(size_t)7);
    float2*   part    = (float2*)p;    p += (size_t)NBLK * 8;             // 50KB

    int E4 = E >> 2;
    int pbh = (E4 + 1023) / 1024;             // hist: 4096 edges/block
    int pbp = (E + PCHUNK - 1) / PCHUNK;      // part: 8192 edges/block, LDS-staged

    hipLaunchKernelGGL(k_zero,     dim3(1),               dim3(512), 0, stream, ghist, NB);
    hipLaunchKernelGGL(k_bhist,    dim3(pbh),             dim3(256), 0, stream, ei, ghist, E, NB);
    hipLaunchKernelGGL(k_bscan,    dim3(1),               dim3(512), 0, stream, ghist, base, cursor, nstart, NB, N, E);
    hipLaunchKernelGGL(k_bpart,    dim3(pbp),             dim3(512), 0, stream, ei, cursor, sorted, E, NB);
    hipLaunchKernelGGL(k_bdeg2,    dim3(NB),              dim3(256), 0, stream, base, sorted, nstart, dinv, N);
    hipLaunchKernelGGL(k_bsort,    dim3(NB),              dim3(256), 0, stream, base, nstart, sorted, sorted2, N);
    hipLaunchKernelGGL(k_gemm,     dim3((N + 255) / 256), dim3(256), 0, stream, x, W, dinv, hs, N);
    hipLaunchKernelGGL(k_agg3,     dim3(NBLK),            dim3(256), 0, stream, nstart, sorted2, hs, dinv, bias, agg, part, N);
    hipLaunchKernelGGL(k_statsred, dim3(1),               dim3(256), 0, stream, part, scal, NBLK);
    hipLaunchKernelGGL(k_final,    dim3((B + 1) / 2),     dim3(256), 0, stream, agg, batch, trans, bias,
                       ln_w, ln_b, prelu_a, scal, out, B, 1.0f / (float)(N * 16));
}

// Round 2
// 302.447 us; speedup vs baseline: 1.2068x; 1.0656x over previous
//
#include <hip/hip_runtime.h>

#define EPS 1e-5f
#define BSHIFT 8
#define BSIZE  256
#define NBMAX  512   // covers N up to 131072 with 256-node buckets
#define PCHUNK 8192  // edges per chunk for hist/part blocks
#define LCAP   12288 // LDS CSR capacity (48KB); avg bucket ~8184, +45 sigma headroom

__device__ __forceinline__ unsigned short f2bf(float f) {
    unsigned u = __float_as_uint(f);
    u += 0x7FFFu + ((u >> 16) & 1u);     // round-to-nearest-even
    return (unsigned short)(u >> 16);
}
__device__ __forceinline__ float bf2f(unsigned short s) {
    return __uint_as_float(((unsigned)s) << 16);
}
__device__ __forceinline__ void acc8(float* acc, uint4 v) {
    acc[0] += bf2f((unsigned short)(v.x & 0xFFFFu)); acc[1] += bf2f((unsigned short)(v.x >> 16));
    acc[2] += bf2f((unsigned short)(v.y & 0xFFFFu)); acc[3] += bf2f((unsigned short)(v.y >> 16));
    acc[4] += bf2f((unsigned short)(v.z & 0xFFFFu)); acc[5] += bf2f((unsigned short)(v.z >> 16));
    acc[6] += bf2f((unsigned short)(v.w & 0xFFFFu)); acc[7] += bf2f((unsigned short)(v.w >> 16));
}

__global__ __launch_bounds__(512) void k_zero(unsigned* ghist, int NB) {
    int t = threadIdx.x;
    if (t < NB) ghist[t] = 0u;
}

// bucket histogram over 8192-edge chunks (same chunking as k_bpart);
// stores per-chunk counts to blkhist so k_bpart can skip its hist phase.
__global__ __launch_bounds__(512) void k_bhist(const int* __restrict__ ei,
                                               unsigned* __restrict__ ghist,
                                               unsigned* __restrict__ blkhist,
                                               int E, int NB) {
    __shared__ unsigned sh[NBMAX];
    int t = threadIdx.x;
    for (int i = t; i < NB; i += 512) sh[i] = 0u;
    __syncthreads();
    const int4* dst4 = (const int4*)(ei + E);
    int E4 = E >> 2;
    int base4 = blockIdx.x * (PCHUNK / 4);
#pragma unroll
    for (int i = 0; i < PCHUNK / 4 / 512; i++) {
        int idx = base4 + i * 512 + t;
        if (idx < E4) {
            int4 d = dst4[idx];
            atomicAdd(&sh[d.x >> BSHIFT], 1u);
            atomicAdd(&sh[d.y >> BSHIFT], 1u);
            atomicAdd(&sh[d.z >> BSHIFT], 1u);
            atomicAdd(&sh[d.w >> BSHIFT], 1u);
        }
    }
    __syncthreads();
    unsigned* bh = blkhist + (size_t)blockIdx.x * NBMAX;
    for (int i = t; i < NB; i += 512) {
        unsigned c = sh[i];
        bh[i] = c;
        if (c) atomicAdd(&ghist[i], c);
    }
}

// exclusive scan of ghist[NB] (NB <= 512) -> base, cursor; sentinels
__global__ __launch_bounds__(512) void k_bscan(const unsigned* __restrict__ ghist,
                                               unsigned* __restrict__ base,
                                               unsigned* __restrict__ cursor,
                                               unsigned* __restrict__ nstart,
                                               int NB, int N, int E) {
    __shared__ unsigned sh[512];
    int t = threadIdx.x;
    unsigned v = (t < NB) ? ghist[t] : 0u;
    sh[t] = v;
    __syncthreads();
    for (int off = 1; off < 512; off <<= 1) {
        unsigned a = (t >= off) ? sh[t - off] : 0u;
        __syncthreads();
        sh[t] += a;
        __syncthreads();
    }
    if (t < NB) { unsigned ex = sh[t] - v; base[t] = ex; cursor[t] = ex; }
    if (t == 0) { base[NB] = (unsigned)E; nstart[N] = (unsigned)E; }
}

// partition edges into bucket streams; packed u32 = src | (dst&255)<<17.
// LDS-staged multisplit; per-chunk hist comes precomputed from blkhist.
__global__ __launch_bounds__(512) void k_bpart(const int* __restrict__ ei,
                                               const unsigned* __restrict__ blkhist,
                                               unsigned* __restrict__ cursor,
                                               unsigned* __restrict__ sorted, int E, int NB) {
    __shared__ unsigned cnt[NBMAX];          // per-bucket count, then rank counter
    __shared__ unsigned lbase[NBMAX];        // reserved global base per bucket
    __shared__ unsigned loff[NBMAX + 1];     // local exclusive scan
    __shared__ unsigned sh[512];             // scan temp
    __shared__ unsigned stage[PCHUNK];       // 32KB bucket-sorted staging
    __shared__ unsigned short bkt[PCHUNK];   // 16KB bucket id per staged position
    int t = threadIdx.x;
    const unsigned* bh = blkhist + (size_t)blockIdx.x * NBMAX;
    for (int i = t; i < NB; i += 512) cnt[i] = bh[i];
    __syncthreads();
    const int4* src4 = (const int4*)ei;
    const int4* dst4 = (const int4*)(ei + E);
    int E4 = E >> 2;
    int base4 = blockIdx.x * (PCHUNK / 4);
    // phase B: reserve global space per bucket + local exclusive scan
    unsigned v = (t < NB) ? cnt[t] : 0u;
    sh[t] = v;
    if (t < NB) lbase[t] = v ? atomicAdd(&cursor[t], v) : 0u;
    __syncthreads();
    for (int off = 1; off < 512; off <<= 1) {
        unsigned a = (t >= off) ? sh[t - off] : 0u;
        __syncthreads();
        sh[t] += a;
        __syncthreads();
    }
    if (t < NB) { loff[t] = sh[t] - v; cnt[t] = 0u; }   // cnt reused as rank ctr
    if (t == NB - 1) loff[NB] = sh[t];                  // total staged count
    __syncthreads();
    // phase C1: fill bucket-of-position (writes bkt[], disjoint from stage[])
    for (int b = t; b < NB; b += 512) {
        unsigned s = loff[b], e2 = loff[b + 1];
        for (unsigned j = s; j < e2; j++) bkt[j] = (unsigned short)b;
    }
    // phase C2: scatter edges into stage in bucket-sorted order
#pragma unroll
    for (int i = 0; i < PCHUNK / 4 / 512; i++) {
        int idx = base4 + i * 512 + t;
        if (idx < E4) {
            int4 s = src4[idx];
            int4 d = dst4[idx];
            int b; unsigned r;
            b = d.x >> BSHIFT; r = atomicAdd(&cnt[b], 1u);
            stage[loff[b] + r] = (unsigned)s.x | ((unsigned)(d.x & (BSIZE - 1)) << 17);
            b = d.y >> BSHIFT; r = atomicAdd(&cnt[b], 1u);
            stage[loff[b] + r] = (unsigned)s.y | ((unsigned)(d.y & (BSIZE - 1)) << 17);
            b = d.z >> BSHIFT; r = atomicAdd(&cnt[b], 1u);
            stage[loff[b] + r] = (unsigned)s.z | ((unsigned)(d.z & (BSIZE - 1)) << 17);
            b = d.w >> BSHIFT; r = atomicAdd(&cnt[b], 1u);
            stage[loff[b] + r] = (unsigned)s.w | ((unsigned)(d.w & (BSIZE - 1)) << 17);
        }
    }
    __syncthreads();
    // phase D: run-contiguous writeout
    unsigned total = loff[NB];
    for (unsigned i = t; i < total; i += 512) {
        unsigned b = bkt[i];
        sorted[lbase[b] + (i - loff[b])] = stage[i];
    }
}

// per-bucket degree count + block scan -> nstart (global CSR row starts) + dinv
__global__ __launch_bounds__(256) void k_bdeg2(const unsigned* __restrict__ base,
                                               const unsigned* __restrict__ sorted,
                                               unsigned* __restrict__ nstart,
                                               float* __restrict__ dinv, int N) {
    __shared__ unsigned deg[BSIZE];
    int b = blockIdx.x, t = threadIdx.x;
    deg[t] = 0u;
    __syncthreads();
    unsigned s0 = base[b], s1 = base[b + 1];
    for (unsigned j = s0 + t; j < s1; j += 256)
        atomicAdd(&deg[sorted[j] >> 17], 1u);
    __syncthreads();
    unsigned d0 = deg[t];
    int lane = t & 63, wid = t >> 6;
    unsigned inc = d0;
    for (int off = 1; off < 64; off <<= 1) {
        unsigned u = __shfl_up(inc, off, 64);
        if (lane >= off) inc += u;
    }
    __shared__ unsigned wsum[4];
    if (lane == 63) wsum[wid] = inc;
    __syncthreads();
    unsigned wbase = 0;
    for (int w = 0; w < wid; w++) wbase += wsum[w];
    unsigned excl = wbase + inc - d0;
    int node = (b << BSHIFT) + t;
    if (node < N) {
        nstart[node] = s0 + excl;
        dinv[node] = rsqrtf((float)(d0 + 1u));   // +1 = self-loop
    }
}

// hs[n][r] = (sum_k x[n][k]*W[r][k]) * dinv[n], stored bf16.
__global__ __launch_bounds__(256) void k_gemm(const float* __restrict__ x,
                                              const float* __restrict__ W,
                                              const float* __restrict__ dinv,
                                              unsigned short* __restrict__ hs, int N) {
    __shared__ float ws[16 * 256];       // W fp32, 16KB
    int t = threadIdx.x;
    for (int i = t; i < 1024; i += 256) ((float4*)ws)[i] = ((const float4*)W)[i];
    __syncthreads();
    int node = blockIdx.x * 256 + t;
    if (node >= N) return;
    const float4* xr = (const float4*)(x + (size_t)node * 256);
    float acc[16];
#pragma unroll
    for (int r = 0; r < 16; r++) acc[r] = 0.f;
#pragma unroll 4
    for (int k = 0; k < 64; k++) {
        float4 a = xr[k];
#pragma unroll
        for (int r = 0; r < 16; r++) {
            float4 w = ((const float4*)ws)[r * 64 + k];   // wave-broadcast LDS read
            acc[r] += a.x * w.x + a.y * w.y + a.z * w.z + a.w * w.w;
        }
    }
    float dv = dinv[node];
    unsigned pk[8];
#pragma unroll
    for (int i = 0; i < 8; i++)
        pk[i] = (unsigned)f2bf(acc[2 * i] * dv) | ((unsigned)f2bf(acc[2 * i + 1] * dv) << 16);
    uint4* dst = (uint4*)(hs + (size_t)node * 16);
    dst[0] = make_uint4(pk[0], pk[1], pk[2], pk[3]);
    dst[1] = make_uint4(pk[4], pk[5], pk[6], pk[7]);
}

// FUSED counting-sort placement + pull aggregation. One block per bucket:
// reads sorted[s0..s1) once, places entries into an LDS-resident CSR
// (positions = nstart - s0), then aggregates 16 nodes/pass x 16 passes,
// gathering hs (L2-resident). Eliminates the sorted2 global round-trip.
// Fallback to global scratch if a bucket exceeds LCAP (cannot happen for
// uniform-random edges; guarded for correctness).
__global__ __launch_bounds__(256) void k_aggf(const unsigned* __restrict__ base,
                                              const unsigned* __restrict__ nstart,
                                              const unsigned* __restrict__ sorted,
                                              const unsigned short* __restrict__ hs,
                                              const float* __restrict__ dinv,
                                              const float* __restrict__ bias,
                                              float* __restrict__ agg,
                                              float2* __restrict__ part,
                                              unsigned* __restrict__ scratch, int N) {
    __shared__ unsigned buf[LCAP];           // 48KB LDS CSR
    __shared__ unsigned cur0[BSIZE + 1];     // local row starts (+ total)
    __shared__ unsigned curv[BSIZE];         // placement cursors
    __shared__ float ss[4], qq[4];
    int b = blockIdx.x, t = threadIdx.x;
    unsigned s0 = base[b], s1 = base[b + 1];
    unsigned len = s1 - s0;
    int node = (b << BSHIFT) + t;
    unsigned ns = (node < N) ? nstart[node] : s1;
    cur0[t] = ns - s0;
    curv[t] = ns - s0;
    if (t == 0) cur0[BSIZE] = len;
    __syncthreads();
    bool fit = (len <= (unsigned)LCAP);
    if (fit) {
        for (unsigned j = t; j < len; j += 256) {
            unsigned u = sorted[s0 + j];
            unsigned pos = atomicAdd(&curv[u >> 17], 1u);
            buf[pos] = u & 0x1FFFFu;
        }
    } else {
        for (unsigned j = t; j < len; j += 256) {
            unsigned u = sorted[s0 + j];
            unsigned pos = atomicAdd(&curv[u >> 17], 1u);
            scratch[s0 + pos] = u & 0x1FFFFu;
        }
    }
    __syncthreads();
    int g = t >> 4, r = t & 15;
    int sub = r >> 1;                    // row offset 0..7
    int half = r & 1;                    // channel half
    float sacc = 0.f, qacc = 0.f;
#pragma unroll 1
    for (int p = 0; p < 16; p++) {
        int dloc = p * 16 + g;
        int d = (b << BSHIFT) + dloc;
        float acc[8];
#pragma unroll
        for (int c = 0; c < 8; c++) acc[c] = 0.f;
        if (d < N) {
            unsigned l0 = cur0[dloc], l1 = cur0[dloc + 1];
            for (unsigned j = l0; j < l1; j += 16) {
                unsigned row0 = j + sub, row1 = j + 8 + sub;
                bool p0 = row0 < l1, p1 = row1 < l1;
                unsigned i0 = 0, i1 = 0;
                if (fit) {
                    if (p0) i0 = buf[row0];
                    if (p1) i1 = buf[row1];
                } else {
                    if (p0) i0 = scratch[s0 + row0];
                    if (p1) i1 = scratch[s0 + row1];
                }
                uint4 v0, v1;
                if (p0) v0 = ((const uint4*)(hs + (size_t)i0 * 16))[half];
                if (p1) v1 = ((const uint4*)(hs + (size_t)i1 * 16))[half];
                if (p0) acc8(acc, v0);
                if (p1) acc8(acc, v1);
            }
        }
#pragma unroll
        for (int off = 2; off <= 8; off <<= 1) {
#pragma unroll
            for (int c = 0; c < 8; c++) acc[c] += __shfl_down(acc[c], off, 64);
        }
        if (d < N && r < 2) {
            float dd = dinv[d];
            uint4 hv = ((const uint4*)(hs + (size_t)d * 16))[half];
            float self[8];
            self[0] = bf2f((unsigned short)(hv.x & 0xFFFFu)); self[1] = bf2f((unsigned short)(hv.x >> 16));
            self[2] = bf2f((unsigned short)(hv.y & 0xFFFFu)); self[3] = bf2f((unsigned short)(hv.y >> 16));
            self[4] = bf2f((unsigned short)(hv.z & 0xFFFFu)); self[5] = bf2f((unsigned short)(hv.z >> 16));
            self[6] = bf2f((unsigned short)(hv.w & 0xFFFFu)); self[7] = bf2f((unsigned short)(hv.w >> 16));
            float o[8];
#pragma unroll
            for (int c = 0; c < 8; c++) o[c] = (acc[c] + self[c]) * dd;
            float* an = agg + (size_t)d * 16 + half * 8;
            *(float4*)(an)     = make_float4(o[0], o[1], o[2], o[3]);
            *(float4*)(an + 4) = make_float4(o[4], o[5], o[6], o[7]);
            const float* bp = bias + half * 8;
            float4 b0 = *(const float4*)bp, b1 = *(const float4*)(bp + 4);
            float a0 = o[0] + b0.x, a1 = o[1] + b0.y, a2 = o[2] + b0.z, a3 = o[3] + b0.w;
            float a4 = o[4] + b1.x, a5 = o[5] + b1.y, a6 = o[6] + b1.z, a7 = o[7] + b1.w;
            sacc += (a0 + a1) + (a2 + a3) + (a4 + a5) + (a6 + a7);
            qacc += a0 * a0 + a1 * a1 + a2 * a2 + a3 * a3 + a4 * a4 + a5 * a5 + a6 * a6 + a7 * a7;
        }
    }
    for (int off = 32; off > 0; off >>= 1) {
        sacc += __shfl_down(sacc, off, 64);
        qacc += __shfl_down(qacc, off, 64);
    }
    int lane = t & 63, wid = t >> 6;
    if (lane == 0) { ss[wid] = sacc; qq[wid] = qacc; }
    __syncthreads();
    if (t == 0)
        part[b] = make_float2(ss[0] + ss[1] + ss[2] + ss[3],
                              qq[0] + qq[1] + qq[2] + qq[3]);
}

// single-block reduction of per-block partials -> scal
__global__ __launch_bounds__(256) void k_statsred(const float2* __restrict__ part,
                                                  float* __restrict__ scal, int M) {
    int t = threadIdx.x;
    float s = 0.f, q = 0.f;
    for (int i = t; i < M; i += 256) {
        float2 v = part[i];
        s += v.x; q += v.y;
    }
    for (int off = 32; off > 0; off >>= 1) {
        s += __shfl_down(s, off, 64);
        q += __shfl_down(q, off, 64);
    }
    __shared__ float ss[4], qq[4];
    int lane = t & 63, wid = t >> 6;
    if (lane == 0) { ss[wid] = s; qq[wid] = q; }
    __syncthreads();
    if (t == 0) {
        scal[0] = ss[0] + ss[1] + ss[2] + ss[3];
        scal[1] = qq[0] + qq[1] + qq[2] + qq[3];
    }
}

// per batch rows: LN + PReLU on 16 channels, then x trans[16,128] -> out[B,128].
// 8 rows/block: 4x fewer trans re-reads; tl column hoisted to registers.
__global__ __launch_bounds__(256) void k_final(const float* __restrict__ agg,
                                               const int* __restrict__ batch,
                                               const float* __restrict__ trans,
                                               const float* __restrict__ bias,
                                               const float* __restrict__ ln_w,
                                               const float* __restrict__ ln_b,
                                               const float* __restrict__ prelu_a,
                                               const float* __restrict__ scal,
                                               float* __restrict__ out, int B, float invCnt) {
    __shared__ float tl[16 * 128];
    __shared__ float hh[8 * 16];
    const int tid = threadIdx.x;
    for (int i = tid; i < 2048; i += 256) tl[i] = trans[i];
    float mean = scal[0] * invCnt;
    float var  = scal[1] * invCnt - mean * mean;
    float inv  = rsqrtf(var + EPS);
    int row0 = blockIdx.x * 8;
    if (tid < 128) {
        int lr = tid >> 4, r = tid & 15;
        int row = row0 + lr;
        if (row < B) {
            int node = batch[row];
            float v = agg[(size_t)node * 16 + r] + bias[r];
            v = (v - mean) * inv * ln_w[r] + ln_b[r];
            float a = prelu_a[0];
            v = v >= 0.f ? v : a * v;
            hh[lr * 16 + r] = v;
        }
    }
    __syncthreads();
    int d = tid & 127, hlf = tid >> 7;
    float tv[16];
#pragma unroll
    for (int r = 0; r < 16; r++) tv[r] = tl[r * 128 + d];
#pragma unroll
    for (int rr = 0; rr < 4; rr++) {
        int lr = rr * 2 + hlf;
        int row = row0 + lr;
        if (row < B) {
            const float* hrow = hh + lr * 16;
            float acc = 0.f;
#pragma unroll
            for (int r = 0; r < 16; r++) acc += hrow[r] * tv[r];
            out[(size_t)row * 128 + d] = acc;
        }
    }
}

extern "C" void kernel_launch(void* const* d_in, const int* in_sizes, int n_in,
                              void* d_out, int out_size, void* d_ws, size_t ws_size,
                              hipStream_t stream) {
    const float* x       = (const float*)d_in[0];
    const int*   ei      = (const int*)d_in[1];
    const float* trans   = (const float*)d_in[2];
    const int*   batch   = (const int*)d_in[3];
    const float* W       = (const float*)d_in[4];
    const float* bias    = (const float*)d_in[5];
    const float* ln_w    = (const float*)d_in[6];
    const float* ln_b    = (const float*)d_in[7];
    const float* prelu_a = (const float*)d_in[8];
    float* out = (float*)d_out;

    const int N = in_sizes[0] / 256;   // 100000
    const int E = in_sizes[1] / 2;     // 3200000
    const int B = in_sizes[3];         // 16384
    const int NB = (N + BSIZE - 1) >> BSHIFT;   // 391
    const int pbp = (E + PCHUNK - 1) / PCHUNK;  // 391 chunks

    char* p = (char*)d_ws;
    unsigned short* hs = (unsigned short*)p;  p += (size_t)N * 16 * 2;    // 3.2MB bf16
    float*    agg     = (float*)p;     p += (size_t)N * 16 * 4;           // 6.4MB
    unsigned* sorted  = (unsigned*)p;  p += (size_t)E * 4;                // 12.8MB
    unsigned* scratch = (unsigned*)p;  p += (size_t)E * 4;                // 12.8MB (fallback only)
    unsigned* blkhist = (unsigned*)p;  p += (size_t)pbp * NBMAX * 4;      // 800KB
    float*    dinv    = (float*)p;     p += (size_t)N * 4;
    unsigned* nstart  = (unsigned*)p;  p += (size_t)(N + 1) * 4;
    unsigned* ghist   = (unsigned*)p;  p += NBMAX * 4;
    unsigned* base    = (unsigned*)p;  p += (NBMAX + 1) * 4;
    unsigned* cursor  = (unsigned*)p;  p += NBMAX * 4;
    float*    scal    = (float*)p;     p += 2 * 4;
    p = (char*)(((size_t)p + 7) & ~(size_t)7);
    float2*   part    = (float2*)p;    p += (size_t)NB * 8;

    hipLaunchKernelGGL(k_zero,     dim3(1),               dim3(512), 0, stream, ghist, NB);
    hipLaunchKernelGGL(k_bhist,    dim3(pbp),             dim3(512), 0, stream, ei, ghist, blkhist, E, NB);
    hipLaunchKernelGGL(k_bscan,    dim3(1),               dim3(512), 0, stream, ghist, base, cursor, nstart, NB, N, E);
    hipLaunchKernelGGL(k_bpart,    dim3(pbp),             dim3(512), 0, stream, ei, blkhist, cursor, sorted, E, NB);
    hipLaunchKernelGGL(k_bdeg2,    dim3(NB),              dim3(256), 0, stream, base, sorted, nstart, dinv, N);
    hipLaunchKernelGGL(k_gemm,     dim3((N + 255) / 256), dim3(256), 0, stream, x, W, dinv, hs, N);
    hipLaunchKernelGGL(k_aggf,     dim3(NB),              dim3(256), 0, stream, base, nstart, sorted, hs, dinv, bias, agg, part, scratch, N);
    hipLaunchKernelGGL(k_statsred, dim3(1),               dim3(256), 0, stream, part, scal, NB);
    hipLaunchKernelGGL(k_final,    dim3((B + 7) / 8),     dim3(256), 0, stream, agg, batch, trans, bias,
                       ln_w, ln_b, prelu_a, scal, out, B, 1.0f / (float)(N * 16));
}

// Round 3
// 292.628 us; speedup vs baseline: 1.2473x; 1.0336x over previous
//
#include <hip/hip_runtime.h>

#define EPS 1e-5f
#define BSHIFT 8
#define BSIZE  256
#define NBMAX  512   // covers N up to 131072 with 256-node buckets
#define PCHUNK 8192  // edges per chunk for hist/part blocks
#define LCAP   12288 // LDS CSR capacity (48KB); avg bucket ~8184, +45 sigma headroom

typedef short bf16x8 __attribute__((ext_vector_type(8)));
typedef float f32x4  __attribute__((ext_vector_type(4)));

__device__ __forceinline__ unsigned short f2bf(float f) {
    unsigned u = __float_as_uint(f);
    u += 0x7FFFu + ((u >> 16) & 1u);     // round-to-nearest-even
    return (unsigned short)(u >> 16);
}
__device__ __forceinline__ float bf2f(unsigned short s) {
    return __uint_as_float(((unsigned)s) << 16);
}
__device__ __forceinline__ void acc8(float* acc, uint4 v) {
    acc[0] += bf2f((unsigned short)(v.x & 0xFFFFu)); acc[1] += bf2f((unsigned short)(v.x >> 16));
    acc[2] += bf2f((unsigned short)(v.y & 0xFFFFu)); acc[3] += bf2f((unsigned short)(v.y >> 16));
    acc[4] += bf2f((unsigned short)(v.z & 0xFFFFu)); acc[5] += bf2f((unsigned short)(v.z >> 16));
    acc[6] += bf2f((unsigned short)(v.w & 0xFFFFu)); acc[7] += bf2f((unsigned short)(v.w >> 16));
}
// split fp32 -> bf16 hi + bf16 lo (residual); x = hi + lo + O(2^-18)
__device__ __forceinline__ void cvt_hilo(const float* f, bf16x8& hi, bf16x8& lo) {
#pragma unroll
    for (int j = 0; j < 8; j++) {
        unsigned short h = f2bf(f[j]);
        hi[j] = (short)h;
        lo[j] = (short)f2bf(f[j] - bf2f(h));
    }
}
__device__ __forceinline__ void gload_lds16(const float* g, float* l) {
    __builtin_amdgcn_global_load_lds((const __attribute__((address_space(1))) void*)g,
                                     (__attribute__((address_space(3))) void*)l, 16, 0, 0);
}

__global__ __launch_bounds__(512) void k_zero(unsigned* ghist, int NB) {
    int t = threadIdx.x;
    if (t < NB) ghist[t] = 0u;
}

// bucket histogram over 8192-edge chunks (same chunking as k_bpart);
// stores per-chunk counts to blkhist so k_bpart can skip its hist phase.
__global__ __launch_bounds__(512) void k_bhist(const int* __restrict__ ei,
                                               unsigned* __restrict__ ghist,
                                               unsigned* __restrict__ blkhist,
                                               int E, int NB) {
    __shared__ unsigned sh[NBMAX];
    int t = threadIdx.x;
    for (int i = t; i < NB; i += 512) sh[i] = 0u;
    __syncthreads();
    const int4* dst4 = (const int4*)(ei + E);
    int E4 = E >> 2;
    int base4 = blockIdx.x * (PCHUNK / 4);
#pragma unroll
    for (int i = 0; i < PCHUNK / 4 / 512; i++) {
        int idx = base4 + i * 512 + t;
        if (idx < E4) {
            int4 d = dst4[idx];
            atomicAdd(&sh[d.x >> BSHIFT], 1u);
            atomicAdd(&sh[d.y >> BSHIFT], 1u);
            atomicAdd(&sh[d.z >> BSHIFT], 1u);
            atomicAdd(&sh[d.w >> BSHIFT], 1u);
        }
    }
    __syncthreads();
    unsigned* bh = blkhist + (size_t)blockIdx.x * NBMAX;
    for (int i = t; i < NB; i += 512) {
        unsigned c = sh[i];
        bh[i] = c;
        if (c) atomicAdd(&ghist[i], c);
    }
}

// exclusive scan of ghist[NB] (NB <= 512) -> base, cursor; sentinels
__global__ __launch_bounds__(512) void k_bscan(const unsigned* __restrict__ ghist,
                                               unsigned* __restrict__ base,
                                               unsigned* __restrict__ cursor,
                                               unsigned* __restrict__ nstart,
                                               int NB, int N, int E) {
    __shared__ unsigned sh[512];
    int t = threadIdx.x;
    unsigned v = (t < NB) ? ghist[t] : 0u;
    sh[t] = v;
    __syncthreads();
    for (int off = 1; off < 512; off <<= 1) {
        unsigned a = (t >= off) ? sh[t - off] : 0u;
        __syncthreads();
        sh[t] += a;
        __syncthreads();
    }
    if (t < NB) { unsigned ex = sh[t] - v; base[t] = ex; cursor[t] = ex; }
    if (t == 0) { base[NB] = (unsigned)E; nstart[N] = (unsigned)E; }
}

// partition edges into bucket streams; packed u32 = src | (dst&255)<<17.
// LDS-staged multisplit; per-chunk hist comes precomputed from blkhist.
__global__ __launch_bounds__(512) void k_bpart(const int* __restrict__ ei,
                                               const unsigned* __restrict__ blkhist,
                                               unsigned* __restrict__ cursor,
                                               unsigned* __restrict__ sorted, int E, int NB) {
    __shared__ unsigned cnt[NBMAX];          // per-bucket count, then rank counter
    __shared__ unsigned lbase[NBMAX];        // reserved global base per bucket
    __shared__ unsigned loff[NBMAX + 1];     // local exclusive scan
    __shared__ unsigned sh[512];             // scan temp
    __shared__ unsigned stage[PCHUNK];       // 32KB bucket-sorted staging
    __shared__ unsigned short bkt[PCHUNK];   // 16KB bucket id per staged position
    int t = threadIdx.x;
    const unsigned* bh = blkhist + (size_t)blockIdx.x * NBMAX;
    for (int i = t; i < NB; i += 512) cnt[i] = bh[i];
    __syncthreads();
    const int4* src4 = (const int4*)ei;
    const int4* dst4 = (const int4*)(ei + E);
    int E4 = E >> 2;
    int base4 = blockIdx.x * (PCHUNK / 4);
    // phase B: reserve global space per bucket + local exclusive scan
    unsigned v = (t < NB) ? cnt[t] : 0u;
    sh[t] = v;
    if (t < NB) lbase[t] = v ? atomicAdd(&cursor[t], v) : 0u;
    __syncthreads();
    for (int off = 1; off < 512; off <<= 1) {
        unsigned a = (t >= off) ? sh[t - off] : 0u;
        __syncthreads();
        sh[t] += a;
        __syncthreads();
    }
    if (t < NB) { loff[t] = sh[t] - v; cnt[t] = 0u; }   // cnt reused as rank ctr
    if (t == NB - 1) loff[NB] = sh[t];                  // total staged count
    __syncthreads();
    // phase C1: fill bucket-of-position (writes bkt[], disjoint from stage[])
    for (int b = t; b < NB; b += 512) {
        unsigned s = loff[b], e2 = loff[b + 1];
        for (unsigned j = s; j < e2; j++) bkt[j] = (unsigned short)b;
    }
    // phase C2: scatter edges into stage in bucket-sorted order
#pragma unroll
    for (int i = 0; i < PCHUNK / 4 / 512; i++) {
        int idx = base4 + i * 512 + t;
        if (idx < E4) {
            int4 s = src4[idx];
            int4 d = dst4[idx];
            int b; unsigned r;
            b = d.x >> BSHIFT; r = atomicAdd(&cnt[b], 1u);
            stage[loff[b] + r] = (unsigned)s.x | ((unsigned)(d.x & (BSIZE - 1)) << 17);
            b = d.y >> BSHIFT; r = atomicAdd(&cnt[b], 1u);
            stage[loff[b] + r] = (unsigned)s.y | ((unsigned)(d.y & (BSIZE - 1)) << 17);
            b = d.z >> BSHIFT; r = atomicAdd(&cnt[b], 1u);
            stage[loff[b] + r] = (unsigned)s.z | ((unsigned)(d.z & (BSIZE - 1)) << 17);
            b = d.w >> BSHIFT; r = atomicAdd(&cnt[b], 1u);
            stage[loff[b] + r] = (unsigned)s.w | ((unsigned)(d.w & (BSIZE - 1)) << 17);
        }
    }
    __syncthreads();
    // phase D: run-contiguous writeout
    unsigned total = loff[NB];
    for (unsigned i = t; i < total; i += 512) {
        unsigned b = bkt[i];
        sorted[lbase[b] + (i - loff[b])] = stage[i];
    }
}

// per-bucket degree count + block scan -> nstart (global CSR row starts) + dinv
__global__ __launch_bounds__(256) void k_bdeg2(const unsigned* __restrict__ base,
                                               const unsigned* __restrict__ sorted,
                                               unsigned* __restrict__ nstart,
                                               float* __restrict__ dinv, int N) {
    __shared__ unsigned deg[BSIZE];
    int b = blockIdx.x, t = threadIdx.x;
    deg[t] = 0u;
    __syncthreads();
    unsigned s0 = base[b], s1 = base[b + 1];
    for (unsigned j = s0 + t; j < s1; j += 256)
        atomicAdd(&deg[sorted[j] >> 17], 1u);
    __syncthreads();
    unsigned d0 = deg[t];
    int lane = t & 63, wid = t >> 6;
    unsigned inc = d0;
    for (int off = 1; off < 64; off <<= 1) {
        unsigned u = __shfl_up(inc, off, 64);
        if (lane >= off) inc += u;
    }
    __shared__ unsigned wsum[4];
    if (lane == 63) wsum[wid] = inc;
    __syncthreads();
    unsigned wbase = 0;
    for (int w = 0; w < wid; w++) wbase += wsum[w];
    unsigned excl = wbase + inc - d0;
    int node = (b << BSHIFT) + t;
    if (node < N) {
        nstart[node] = s0 + excl;
        dinv[node] = rsqrtf((float)(d0 + 1u));   // +1 = self-loop
    }
}

// MFMA GEMM: hs[n][r] = (sum_k x[n][k]*W[r][k]) * dinv[n], stored bf16.
// bf16x3 split (hi/lo) keeps fp32-level precision; coalesced global_load_lds
// staging (1 instr per 1KB row) replaces the old 64-line-scattered loads.
// 512 persistent blocks x 256 thr; 64-node chunks; 66.5KB LDS -> 2 blocks/CU.
__global__ __launch_bounds__(256) void k_gemm(const float* __restrict__ x,
                                              const float* __restrict__ W,
                                              const float* __restrict__ dinv,
                                              unsigned short* __restrict__ hs,
                                              int N, int NCH) {
    __shared__ float xs[64][260];        // pad 260: even 8-touch/bank frag reads
    int t = threadIdx.x;
    int w = t >> 6, lane = t & 63;
    int lr = lane & 15;                  // A row / B col (r)
    int lk = lane >> 4;                  // k sub-block 0..3
    // preload W fragments (bf16 hi/lo) into registers: lane holds W[lr][kt*32+lk*8+j]
    bf16x8 bh[8], bl[8];
#pragma unroll
    for (int kt = 0; kt < 8; kt++) {
        float wf[8];
        const float* wp = W + lr * 256 + kt * 32 + lk * 8;
        *(float4*)&wf[0] = *(const float4*)wp;
        *(float4*)&wf[4] = *(const float4*)(wp + 4);
        cvt_hilo(wf, bh[kt], bl[kt]);
    }
    for (int ch = blockIdx.x; ch < NCH; ch += gridDim.x) {
        int cb = ch << 6;
        // stage 64 rows (wave w: rows 16w..16w+15), coalesced 1KB per instr
#pragma unroll
        for (int j = 0; j < 16; j++) {
            int row = w * 16 + j;
            int node = cb + row;
            if (node < N)
                gload_lds16(x + (size_t)node * 256 + lane * 4, &xs[row][0]);
        }
        __syncthreads();                 // drains vmcnt -> xs ready
        f32x4 acc = {0.f, 0.f, 0.f, 0.f};
#pragma unroll
        for (int kt = 0; kt < 8; kt++) {
            float af[8];
            const float* ap = &xs[w * 16 + lr][kt * 32 + lk * 8];
            *(float4*)&af[0] = *(const float4*)ap;
            *(float4*)&af[4] = *(const float4*)(ap + 4);
            bf16x8 ah, al;
            cvt_hilo(af, ah, al);
            acc = __builtin_amdgcn_mfma_f32_16x16x32_bf16(ah, bh[kt], acc, 0, 0, 0);
            acc = __builtin_amdgcn_mfma_f32_16x16x32_bf16(al, bh[kt], acc, 0, 0, 0);
            acc = __builtin_amdgcn_mfma_f32_16x16x32_bf16(ah, bl[kt], acc, 0, 0, 0);
        }
        // C layout: col=lane&15 (=r), row=(lane>>4)*4+reg (=node offset)
#pragma unroll
        for (int i = 0; i < 4; i++) {
            int node = cb + w * 16 + lk * 4 + i;
            if (node < N) {
                float dv = dinv[node];
                hs[(size_t)node * 16 + lr] = f2bf(acc[i] * dv);
            }
        }
        __syncthreads();                 // protect xs before next stage
    }
}

// FUSED counting-sort placement + pull aggregation (unchanged from R2).
__global__ __launch_bounds__(256) void k_aggf(const unsigned* __restrict__ base,
                                              const unsigned* __restrict__ nstart,
                                              const unsigned* __restrict__ sorted,
                                              const unsigned short* __restrict__ hs,
                                              const float* __restrict__ dinv,
                                              const float* __restrict__ bias,
                                              float* __restrict__ agg,
                                              float2* __restrict__ part,
                                              unsigned* __restrict__ scratch, int N) {
    __shared__ unsigned buf[LCAP];           // 48KB LDS CSR
    __shared__ unsigned cur0[BSIZE + 1];     // local row starts (+ total)
    __shared__ unsigned curv[BSIZE];         // placement cursors
    __shared__ float ss[4], qq[4];
    int b = blockIdx.x, t = threadIdx.x;
    unsigned s0 = base[b], s1 = base[b + 1];
    unsigned len = s1 - s0;
    int node = (b << BSHIFT) + t;
    unsigned ns = (node < N) ? nstart[node] : s1;
    cur0[t] = ns - s0;
    curv[t] = ns - s0;
    if (t == 0) cur0[BSIZE] = len;
    __syncthreads();
    bool fit = (len <= (unsigned)LCAP);
    if (fit) {
        for (unsigned j = t; j < len; j += 256) {
            unsigned u = sorted[s0 + j];
            unsigned pos = atomicAdd(&curv[u >> 17], 1u);
            buf[pos] = u & 0x1FFFFu;
        }
    } else {
        for (unsigned j = t; j < len; j += 256) {
            unsigned u = sorted[s0 + j];
            unsigned pos = atomicAdd(&curv[u >> 17], 1u);
            scratch[s0 + pos] = u & 0x1FFFFu;
        }
    }
    __syncthreads();
    int g = t >> 4, r = t & 15;
    int sub = r >> 1;                    // row offset 0..7
    int half = r & 1;                    // channel half
    float sacc = 0.f, qacc = 0.f;
#pragma unroll 1
    for (int p = 0; p < 16; p++) {
        int dloc = p * 16 + g;
        int d = (b << BSHIFT) + dloc;
        float acc[8];
#pragma unroll
        for (int c = 0; c < 8; c++) acc[c] = 0.f;
        if (d < N) {
            unsigned l0 = cur0[dloc], l1 = cur0[dloc + 1];
            for (unsigned j = l0; j < l1; j += 16) {
                unsigned row0 = j + sub, row1 = j + 8 + sub;
                bool p0 = row0 < l1, p1 = row1 < l1;
                unsigned i0 = 0, i1 = 0;
                if (fit) {
                    if (p0) i0 = buf[row0];
                    if (p1) i1 = buf[row1];
                } else {
                    if (p0) i0 = scratch[s0 + row0];
                    if (p1) i1 = scratch[s0 + row1];
                }
                uint4 v0, v1;
                if (p0) v0 = ((const uint4*)(hs + (size_t)i0 * 16))[half];
                if (p1) v1 = ((const uint4*)(hs + (size_t)i1 * 16))[half];
                if (p0) acc8(acc, v0);
                if (p1) acc8(acc, v1);
            }
        }
#pragma unroll
        for (int off = 2; off <= 8; off <<= 1) {
#pragma unroll
            for (int c = 0; c < 8; c++) acc[c] += __shfl_down(acc[c], off, 64);
        }
        if (d < N && r < 2) {
            float dd = dinv[d];
            uint4 hv = ((const uint4*)(hs + (size_t)d * 16))[half];
            float self[8];
            self[0] = bf2f((unsigned short)(hv.x & 0xFFFFu)); self[1] = bf2f((unsigned short)(hv.x >> 16));
            self[2] = bf2f((unsigned short)(hv.y & 0xFFFFu)); self[3] = bf2f((unsigned short)(hv.y >> 16));
            self[4] = bf2f((unsigned short)(hv.z & 0xFFFFu)); self[5] = bf2f((unsigned short)(hv.z >> 16));
            self[6] = bf2f((unsigned short)(hv.w & 0xFFFFu)); self[7] = bf2f((unsigned short)(hv.w >> 16));
            float o[8];
#pragma unroll
            for (int c = 0; c < 8; c++) o[c] = (acc[c] + self[c]) * dd;
            float* an = agg + (size_t)d * 16 + half * 8;
            *(float4*)(an)     = make_float4(o[0], o[1], o[2], o[3]);
            *(float4*)(an + 4) = make_float4(o[4], o[5], o[6], o[7]);
            const float* bp = bias + half * 8;
            float4 b0 = *(const float4*)bp, b1 = *(const float4*)(bp + 4);
            float a0 = o[0] + b0.x, a1 = o[1] + b0.y, a2 = o[2] + b0.z, a3 = o[3] + b0.w;
            float a4 = o[4] + b1.x, a5 = o[5] + b1.y, a6 = o[6] + b1.z, a7 = o[7] + b1.w;
            sacc += (a0 + a1) + (a2 + a3) + (a4 + a5) + (a6 + a7);
            qacc += a0 * a0 + a1 * a1 + a2 * a2 + a3 * a3 + a4 * a4 + a5 * a5 + a6 * a6 + a7 * a7;
        }
    }
    for (int off = 32; off > 0; off >>= 1) {
        sacc += __shfl_down(sacc, off, 64);
        qacc += __shfl_down(qacc, off, 64);
    }
    int lane = t & 63, wid = t >> 6;
    if (lane == 0) { ss[wid] = sacc; qq[wid] = qacc; }
    __syncthreads();
    if (t == 0)
        part[b] = make_float2(ss[0] + ss[1] + ss[2] + ss[3],
                              qq[0] + qq[1] + qq[2] + qq[3]);
}

// single-block reduction of per-block partials -> scal
__global__ __launch_bounds__(256) void k_statsred(const float2* __restrict__ part,
                                                  float* __restrict__ scal, int M) {
    int t = threadIdx.x;
    float s = 0.f, q = 0.f;
    for (int i = t; i < M; i += 256) {
        float2 v = part[i];
        s += v.x; q += v.y;
    }
    for (int off = 32; off > 0; off >>= 1) {
        s += __shfl_down(s, off, 64);
        q += __shfl_down(q, off, 64);
    }
    __shared__ float ss[4], qq[4];
    int lane = t & 63, wid = t >> 6;
    if (lane == 0) { ss[wid] = s; qq[wid] = q; }
    __syncthreads();
    if (t == 0) {
        scal[0] = ss[0] + ss[1] + ss[2] + ss[3];
        scal[1] = qq[0] + qq[1] + qq[2] + qq[3];
    }
}

// per batch rows: LN + PReLU on 16 channels, then x trans[16,128] -> out[B,128].
// 8 rows/block; tl column hoisted to registers.
__global__ __launch_bounds__(256) void k_final(const float* __restrict__ agg,
                                               const int* __restrict__ batch,
                                               const float* __restrict__ trans,
                                               const float* __restrict__ bias,
                                               const float* __restrict__ ln_w,
                                               const float* __restrict__ ln_b,
                                               const float* __restrict__ prelu_a,
                                               const float* __restrict__ scal,
                                               float* __restrict__ out, int B, float invCnt) {
    __shared__ float tl[16 * 128];
    __shared__ float hh[8 * 16];
    const int tid = threadIdx.x;
    for (int i = tid; i < 2048; i += 256) tl[i] = trans[i];
    float mean = scal[0] * invCnt;
    float var  = scal[1] * invCnt - mean * mean;
    float inv  = rsqrtf(var + EPS);
    int row0 = blockIdx.x * 8;
    if (tid < 128) {
        int lr = tid >> 4, r = tid & 15;
        int row = row0 + lr;
        if (row < B) {
            int node = batch[row];
            float v = agg[(size_t)node * 16 + r] + bias[r];
            v = (v - mean) * inv * ln_w[r] + ln_b[r];
            float a = prelu_a[0];
            v = v >= 0.f ? v : a * v;
            hh[lr * 16 + r] = v;
        }
    }
    __syncthreads();
    int d = tid & 127, hlf = tid >> 7;
    float tv[16];
#pragma unroll
    for (int r = 0; r < 16; r++) tv[r] = tl[r * 128 + d];
#pragma unroll
    for (int rr = 0; rr < 4; rr++) {
        int lr = rr * 2 + hlf;
        int row = row0 + lr;
        if (row < B) {
            const float* hrow = hh + lr * 16;
            float acc = 0.f;
#pragma unroll
            for (int r = 0; r < 16; r++) acc += hrow[r] * tv[r];
            out[(size_t)row * 128 + d] = acc;
        }
    }
}

extern "C" void kernel_launch(void* const* d_in, const int* in_sizes, int n_in,
                              void* d_out, int out_size, void* d_ws, size_t ws_size,
                              hipStream_t stream) {
    const float* x       = (const float*)d_in[0];
    const int*   ei      = (const int*)d_in[1];
    const float* trans   = (const float*)d_in[2];
    const int*   batch   = (const int*)d_in[3];
    const float* W       = (const float*)d_in[4];
    const float* bias    = (const float*)d_in[5];
    const float* ln_w    = (const float*)d_in[6];
    const float* ln_b    = (const float*)d_in[7];
    const float* prelu_a = (const float*)d_in[8];
    float* out = (float*)d_out;

    const int N = in_sizes[0] / 256;   // 100000
    const int E = in_sizes[1] / 2;     // 3200000
    const int B = in_sizes[3];         // 16384
    const int NB = (N + BSIZE - 1) >> BSHIFT;   // 391
    const int pbp = (E + PCHUNK - 1) / PCHUNK;  // 391 chunks
    const int NCH = (N + 63) / 64;     // 1563 gemm chunks

    char* p = (char*)d_ws;
    unsigned short* hs = (unsigned short*)p;  p += (size_t)N * 16 * 2;    // 3.2MB bf16
    float*    agg     = (float*)p;     p += (size_t)N * 16 * 4;           // 6.4MB
    unsigned* sorted  = (unsigned*)p;  p += (size_t)E * 4;                // 12.8MB
    unsigned* scratch = (unsigned*)p;  p += (size_t)E * 4;                // 12.8MB (fallback only)
    unsigned* blkhist = (unsigned*)p;  p += (size_t)pbp * NBMAX * 4;      // 800KB
    float*    dinv    = (float*)p;     p += (size_t)N * 4;
    unsigned* nstart  = (unsigned*)p;  p += (size_t)(N + 1) * 4;
    unsigned* ghist   = (unsigned*)p;  p += NBMAX * 4;
    unsigned* base    = (unsigned*)p;  p += (NBMAX + 1) * 4;
    unsigned* cursor  = (unsigned*)p;  p += NBMAX * 4;
    float*    scal    = (float*)p;     p += 2 * 4;
    p = (char*)(((size_t)p + 7) & ~(size_t)7);
    float2*   part    = (float2*)p;    p += (size_t)NB * 8;

    hipLaunchKernelGGL(k_zero,     dim3(1),               dim3(512), 0, stream, ghist, NB);
    hipLaunchKernelGGL(k_bhist,    dim3(pbp),             dim3(512), 0, stream, ei, ghist, blkhist, E, NB);
    hipLaunchKernelGGL(k_bscan,    dim3(1),               dim3(512), 0, stream, ghist, base, cursor, nstart, NB, N, E);
    hipLaunchKernelGGL(k_bpart,    dim3(pbp),             dim3(512), 0, stream, ei, blkhist, cursor, sorted, E, NB);
    hipLaunchKernelGGL(k_bdeg2,    dim3(NB),              dim3(256), 0, stream, base, sorted, nstart, dinv, N);
    hipLaunchKernelGGL(k_gemm,     dim3(512),             dim3(256), 0, stream, x, W, dinv, hs, N, NCH);
    hipLaunchKernelGGL(k_aggf,     dim3(NB),              dim3(256), 0, stream, base, nstart, sorted, hs, dinv, bias, agg, part, scratch, N);
    hipLaunchKernelGGL(k_statsred, dim3(1),               dim3(256), 0, stream, part, scal, NB);
    hipLaunchKernelGGL(k_final,    dim3((B + 7) / 8),     dim3(256), 0, stream, agg, batch, trans, bias,
                       ln_w, ln_b, prelu_a, scal, out, B, 1.0f / (float)(N * 16));
}

// Round 4
// 279.907 us; speedup vs baseline: 1.3039x; 1.0454x over previous
//
#include <hip/hip_runtime.h>

#define EPS 1e-5f
#define BSHIFT 8
#define BSIZE  256
#define NBMAX  512   // covers N up to 131072 with 256-node buckets
#define PCHUNK 8192  // edges per chunk for hist/part blocks
#define LCAP   12288 // LDS CSR capacity (48KB); avg bucket ~8184, +45 sigma headroom

typedef short bf16x8 __attribute__((ext_vector_type(8)));
typedef float f32x4  __attribute__((ext_vector_type(4)));

__device__ __forceinline__ unsigned short f2bf(float f) {
    unsigned u = __float_as_uint(f);
    u += 0x7FFFu + ((u >> 16) & 1u);     // round-to-nearest-even
    return (unsigned short)(u >> 16);
}
__device__ __forceinline__ float bf2f(unsigned short s) {
    return __uint_as_float(((unsigned)s) << 16);
}
__device__ __forceinline__ void acc8(float* acc, uint4 v) {
    acc[0] += bf2f((unsigned short)(v.x & 0xFFFFu)); acc[1] += bf2f((unsigned short)(v.x >> 16));
    acc[2] += bf2f((unsigned short)(v.y & 0xFFFFu)); acc[3] += bf2f((unsigned short)(v.y >> 16));
    acc[4] += bf2f((unsigned short)(v.z & 0xFFFFu)); acc[5] += bf2f((unsigned short)(v.z >> 16));
    acc[6] += bf2f((unsigned short)(v.w & 0xFFFFu)); acc[7] += bf2f((unsigned short)(v.w >> 16));
}
// split fp32 -> bf16 hi + bf16 lo (residual); x = hi + lo + O(2^-18)
__device__ __forceinline__ void cvt_hilo(const float* f, bf16x8& hi, bf16x8& lo) {
#pragma unroll
    for (int j = 0; j < 8; j++) {
        unsigned short h = f2bf(f[j]);
        hi[j] = (short)h;
        lo[j] = (short)f2bf(f[j] - bf2f(h));
    }
}

__global__ __launch_bounds__(512) void k_zero(unsigned* ghist, int NB) {
    int t = threadIdx.x;
    if (t < NB) ghist[t] = 0u;
}

// bucket histogram over 8192-edge chunks (same chunking as k_bpart);
// stores per-chunk counts to blkhist so k_bpart can skip its hist phase.
__global__ __launch_bounds__(512) void k_bhist(const int* __restrict__ ei,
                                               unsigned* __restrict__ ghist,
                                               unsigned* __restrict__ blkhist,
                                               int E, int NB) {
    __shared__ unsigned sh[NBMAX];
    int t = threadIdx.x;
    for (int i = t; i < NB; i += 512) sh[i] = 0u;
    __syncthreads();
    const int4* dst4 = (const int4*)(ei + E);
    int E4 = E >> 2;
    int base4 = blockIdx.x * (PCHUNK / 4);
#pragma unroll
    for (int i = 0; i < PCHUNK / 4 / 512; i++) {
        int idx = base4 + i * 512 + t;
        if (idx < E4) {
            int4 d = dst4[idx];
            atomicAdd(&sh[d.x >> BSHIFT], 1u);
            atomicAdd(&sh[d.y >> BSHIFT], 1u);
            atomicAdd(&sh[d.z >> BSHIFT], 1u);
            atomicAdd(&sh[d.w >> BSHIFT], 1u);
        }
    }
    __syncthreads();
    unsigned* bh = blkhist + (size_t)blockIdx.x * NBMAX;
    for (int i = t; i < NB; i += 512) {
        unsigned c = sh[i];
        bh[i] = c;
        if (c) atomicAdd(&ghist[i], c);
    }
}

// exclusive scan of ghist[NB] (NB <= 512) -> base, cursor; sentinels
__global__ __launch_bounds__(512) void k_bscan(const unsigned* __restrict__ ghist,
                                               unsigned* __restrict__ base,
                                               unsigned* __restrict__ cursor,
                                               unsigned* __restrict__ nstart,
                                               int NB, int N, int E) {
    __shared__ unsigned sh[512];
    int t = threadIdx.x;
    unsigned v = (t < NB) ? ghist[t] : 0u;
    sh[t] = v;
    __syncthreads();
    for (int off = 1; off < 512; off <<= 1) {
        unsigned a = (t >= off) ? sh[t - off] : 0u;
        __syncthreads();
        sh[t] += a;
        __syncthreads();
    }
    if (t < NB) { unsigned ex = sh[t] - v; base[t] = ex; cursor[t] = ex; }
    if (t == 0) { base[NB] = (unsigned)E; nstart[N] = (unsigned)E; }
}

// partition edges into bucket streams; packed u32 = src | (dst&255)<<17.
// LDS-staged multisplit; per-chunk hist comes precomputed from blkhist.
__global__ __launch_bounds__(512) void k_bpart(const int* __restrict__ ei,
                                               const unsigned* __restrict__ blkhist,
                                               unsigned* __restrict__ cursor,
                                               unsigned* __restrict__ sorted, int E, int NB) {
    __shared__ unsigned cnt[NBMAX];          // per-bucket count, then rank counter
    __shared__ unsigned lbase[NBMAX];        // reserved global base per bucket
    __shared__ unsigned loff[NBMAX + 1];     // local exclusive scan
    __shared__ unsigned sh[512];             // scan temp
    __shared__ unsigned stage[PCHUNK];       // 32KB bucket-sorted staging
    __shared__ unsigned short bkt[PCHUNK];   // 16KB bucket id per staged position
    int t = threadIdx.x;
    const unsigned* bh = blkhist + (size_t)blockIdx.x * NBMAX;
    for (int i = t; i < NB; i += 512) cnt[i] = bh[i];
    __syncthreads();
    const int4* src4 = (const int4*)ei;
    const int4* dst4 = (const int4*)(ei + E);
    int E4 = E >> 2;
    int base4 = blockIdx.x * (PCHUNK / 4);
    // phase B: reserve global space per bucket + local exclusive scan
    unsigned v = (t < NB) ? cnt[t] : 0u;
    sh[t] = v;
    if (t < NB) lbase[t] = v ? atomicAdd(&cursor[t], v) : 0u;
    __syncthreads();
    for (int off = 1; off < 512; off <<= 1) {
        unsigned a = (t >= off) ? sh[t - off] : 0u;
        __syncthreads();
        sh[t] += a;
        __syncthreads();
    }
    if (t < NB) { loff[t] = sh[t] - v; cnt[t] = 0u; }   // cnt reused as rank ctr
    if (t == NB - 1) loff[NB] = sh[t];                  // total staged count
    __syncthreads();
    // phase C1: fill bucket-of-position (writes bkt[], disjoint from stage[])
    for (int b = t; b < NB; b += 512) {
        unsigned s = loff[b], e2 = loff[b + 1];
        for (unsigned j = s; j < e2; j++) bkt[j] = (unsigned short)b;
    }
    // phase C2: scatter edges into stage in bucket-sorted order
#pragma unroll
    for (int i = 0; i < PCHUNK / 4 / 512; i++) {
        int idx = base4 + i * 512 + t;
        if (idx < E4) {
            int4 s = src4[idx];
            int4 d = dst4[idx];
            int b; unsigned r;
            b = d.x >> BSHIFT; r = atomicAdd(&cnt[b], 1u);
            stage[loff[b] + r] = (unsigned)s.x | ((unsigned)(d.x & (BSIZE - 1)) << 17);
            b = d.y >> BSHIFT; r = atomicAdd(&cnt[b], 1u);
            stage[loff[b] + r] = (unsigned)s.y | ((unsigned)(d.y & (BSIZE - 1)) << 17);
            b = d.z >> BSHIFT; r = atomicAdd(&cnt[b], 1u);
            stage[loff[b] + r] = (unsigned)s.z | ((unsigned)(d.z & (BSIZE - 1)) << 17);
            b = d.w >> BSHIFT; r = atomicAdd(&cnt[b], 1u);
            stage[loff[b] + r] = (unsigned)s.w | ((unsigned)(d.w & (BSIZE - 1)) << 17);
        }
    }
    __syncthreads();
    // phase D: run-contiguous writeout
    unsigned total = loff[NB];
    for (unsigned i = t; i < total; i += 512) {
        unsigned b = bkt[i];
        sorted[lbase[b] + (i - loff[b])] = stage[i];
    }
}

// per-bucket degree count + block scan -> nstart (global CSR row starts) + dinv
// 512 threads: count loop gets 8 waves of TLP; scan done by first 4 waves.
__global__ __launch_bounds__(512) void k_bdeg2(const unsigned* __restrict__ base,
                                               const unsigned* __restrict__ sorted,
                                               unsigned* __restrict__ nstart,
                                               float* __restrict__ dinv, int N) {
    __shared__ unsigned deg[BSIZE];
    __shared__ unsigned wsum[4];
    int b = blockIdx.x, t = threadIdx.x;
    if (t < BSIZE) deg[t] = 0u;
    __syncthreads();
    unsigned s0 = base[b], s1 = base[b + 1];
    for (unsigned j = s0 + t; j < s1; j += 512)
        atomicAdd(&deg[sorted[j] >> 17], 1u);
    __syncthreads();
    unsigned d0 = 0, inc = 0;
    int lane = t & 63, wid = t >> 6;
    if (t < BSIZE) {
        d0 = deg[t];
        inc = d0;
        for (int off = 1; off < 64; off <<= 1) {
            unsigned u = __shfl_up(inc, off, 64);
            if (lane >= off) inc += u;
        }
        if (lane == 63) wsum[wid] = inc;
    }
    __syncthreads();
    if (t < BSIZE) {
        unsigned wbase = 0;
        for (int w = 0; w < wid; w++) wbase += wsum[w];
        unsigned excl = wbase + inc - d0;
        int node = (b << BSHIFT) + t;
        if (node < N) {
            nstart[node] = s0 + excl;
            dinv[node] = rsqrtf((float)(d0 + 1u));   // +1 = self-loop
        }
    }
}

// MFMA GEMM, direct-from-global: hs[n][r] = (sum_k x[n][k]*W[r][k])*dinv[n], bf16.
// No LDS, no barriers: each wave owns a 16-node tile, loads its A fragments
// straight from global (row fully consumed by the same wave across kt -> L1
// absorbs the per-instr line splits). bf16x3 hi/lo split keeps fp32 precision.
// Persistent 512 blocks amortize the W fragment conversion; 4+ waves/SIMD.
__global__ __launch_bounds__(256, 4) void k_gemm(const float* __restrict__ x,
                                                 const float* __restrict__ W,
                                                 const float* __restrict__ dinv,
                                                 unsigned short* __restrict__ hs,
                                                 int N, int NT) {
    int t = threadIdx.x;
    int w = t >> 6, lane = t & 63;
    int lr = lane & 15;                  // A row / B col (r)
    int lk = lane >> 4;                  // k sub-block 0..3
    // preload W fragments (bf16 hi/lo): lane holds W[lr][kt*32+lk*8+j]
    bf16x8 bh[8], bl[8];
#pragma unroll
    for (int kt = 0; kt < 8; kt++) {
        float wf[8];
        const float* wp = W + lr * 256 + kt * 32 + lk * 8;
        *(float4*)&wf[0] = *(const float4*)wp;
        *(float4*)&wf[4] = *(const float4*)(wp + 4);
        cvt_hilo(wf, bh[kt], bl[kt]);
    }
    int nw = gridDim.x * 4;              // total waves
    int wid = blockIdx.x * 4 + w;
    for (int tile = wid; tile < NT; tile += nw) {
        int nb = tile << 4;
        int node = nb + lr;
        const float* xp = x + (size_t)node * 256;
        f32x4 acc = {0.f, 0.f, 0.f, 0.f};
#pragma unroll
        for (int kt = 0; kt < 8; kt++) {
            float af[8];
            if (node < N) {
                const float* ap = xp + kt * 32 + lk * 8;
                *(float4*)&af[0] = *(const float4*)ap;
                *(float4*)&af[4] = *(const float4*)(ap + 4);
            } else {
#pragma unroll
                for (int j = 0; j < 8; j++) af[j] = 0.f;
            }
            bf16x8 ah, al;
            cvt_hilo(af, ah, al);
            acc = __builtin_amdgcn_mfma_f32_16x16x32_bf16(ah, bh[kt], acc, 0, 0, 0);
            acc = __builtin_amdgcn_mfma_f32_16x16x32_bf16(al, bh[kt], acc, 0, 0, 0);
            acc = __builtin_amdgcn_mfma_f32_16x16x32_bf16(ah, bl[kt], acc, 0, 0, 0);
        }
        // C layout: col=lane&15 (=r), row=(lane>>4)*4+reg (=node offset)
#pragma unroll
        for (int i = 0; i < 4; i++) {
            int n2 = nb + lk * 4 + i;
            if (n2 < N) {
                float dv = dinv[n2];
                hs[(size_t)n2 * 16 + lr] = f2bf(acc[i] * dv);
            }
        }
    }
}

// FUSED counting-sort placement + pull aggregation, 512 threads (8 waves of
// TLP for the L2 gathers; aggregation passes 16 -> 8).
__global__ __launch_bounds__(512) void k_aggf(const unsigned* __restrict__ base,
                                              const unsigned* __restrict__ nstart,
                                              const unsigned* __restrict__ sorted,
                                              const unsigned short* __restrict__ hs,
                                              const float* __restrict__ dinv,
                                              const float* __restrict__ bias,
                                              float* __restrict__ agg,
                                              float2* __restrict__ part,
                                              unsigned* __restrict__ scratch, int N) {
    __shared__ unsigned buf[LCAP];           // 48KB LDS CSR
    __shared__ unsigned cur0[BSIZE + 1];     // local row starts (+ total)
    __shared__ unsigned curv[BSIZE];         // placement cursors
    __shared__ float ss[8], qq[8];
    int b = blockIdx.x, t = threadIdx.x;
    unsigned s0 = base[b], s1 = base[b + 1];
    unsigned len = s1 - s0;
    if (t < BSIZE) {
        int node = (b << BSHIFT) + t;
        unsigned ns = (node < N) ? nstart[node] : s1;
        cur0[t] = ns - s0;
        curv[t] = ns - s0;
    }
    if (t == 0) cur0[BSIZE] = len;
    __syncthreads();
    bool fit = (len <= (unsigned)LCAP);
    if (fit) {
        for (unsigned j = t; j < len; j += 512) {
            unsigned u = sorted[s0 + j];
            unsigned pos = atomicAdd(&curv[u >> 17], 1u);
            buf[pos] = u & 0x1FFFFu;
        }
    } else {
        for (unsigned j = t; j < len; j += 512) {
            unsigned u = sorted[s0 + j];
            unsigned pos = atomicAdd(&curv[u >> 17], 1u);
            scratch[s0 + pos] = u & 0x1FFFFu;
        }
    }
    __syncthreads();
    int g = t >> 4, r = t & 15;              // 32 groups of 16 lanes
    int sub = r >> 1;                        // row offset 0..7
    int half = r & 1;                        // channel half
    float sacc = 0.f, qacc = 0.f;
#pragma unroll 1
    for (int p = 0; p < 8; p++) {
        int dloc = p * 32 + g;
        int d = (b << BSHIFT) + dloc;
        float acc[8];
#pragma unroll
        for (int c = 0; c < 8; c++) acc[c] = 0.f;
        if (d < N) {
            unsigned l0 = cur0[dloc], l1 = cur0[dloc + 1];
            for (unsigned j = l0; j < l1; j += 16) {
                unsigned row0 = j + sub, row1 = j + 8 + sub;
                bool p0 = row0 < l1, p1 = row1 < l1;
                unsigned i0 = 0, i1 = 0;
                if (fit) {
                    if (p0) i0 = buf[row0];
                    if (p1) i1 = buf[row1];
                } else {
                    if (p0) i0 = scratch[s0 + row0];
                    if (p1) i1 = scratch[s0 + row1];
                }
                uint4 v0, v1;
                if (p0) v0 = ((const uint4*)(hs + (size_t)i0 * 16))[half];
                if (p1) v1 = ((const uint4*)(hs + (size_t)i1 * 16))[half];
                if (p0) acc8(acc, v0);
                if (p1) acc8(acc, v1);
            }
        }
#pragma unroll
        for (int off = 2; off <= 8; off <<= 1) {
#pragma unroll
            for (int c = 0; c < 8; c++) acc[c] += __shfl_down(acc[c], off, 64);
        }
        if (d < N && r < 2) {
            float dd = dinv[d];
            uint4 hv = ((const uint4*)(hs + (size_t)d * 16))[half];
            float self[8];
            self[0] = bf2f((unsigned short)(hv.x & 0xFFFFu)); self[1] = bf2f((unsigned short)(hv.x >> 16));
            self[2] = bf2f((unsigned short)(hv.y & 0xFFFFu)); self[3] = bf2f((unsigned short)(hv.y >> 16));
            self[4] = bf2f((unsigned short)(hv.z & 0xFFFFu)); self[5] = bf2f((unsigned short)(hv.z >> 16));
            self[6] = bf2f((unsigned short)(hv.w & 0xFFFFu)); self[7] = bf2f((unsigned short)(hv.w >> 16));
            float o[8];
#pragma unroll
            for (int c = 0; c < 8; c++) o[c] = (acc[c] + self[c]) * dd;
            float* an = agg + (size_t)d * 16 + half * 8;
            *(float4*)(an)     = make_float4(o[0], o[1], o[2], o[3]);
            *(float4*)(an + 4) = make_float4(o[4], o[5], o[6], o[7]);
            const float* bp = bias + half * 8;
            float4 b0 = *(const float4*)bp, b1 = *(const float4*)(bp + 4);
            float a0 = o[0] + b0.x, a1 = o[1] + b0.y, a2 = o[2] + b0.z, a3 = o[3] + b0.w;
            float a4 = o[4] + b1.x, a5 = o[5] + b1.y, a6 = o[6] + b1.z, a7 = o[7] + b1.w;
            sacc += (a0 + a1) + (a2 + a3) + (a4 + a5) + (a6 + a7);
            qacc += a0 * a0 + a1 * a1 + a2 * a2 + a3 * a3 + a4 * a4 + a5 * a5 + a6 * a6 + a7 * a7;
        }
    }
    for (int off = 32; off > 0; off >>= 1) {
        sacc += __shfl_down(sacc, off, 64);
        qacc += __shfl_down(qacc, off, 64);
    }
    int lane = t & 63, wid = t >> 6;
    if (lane == 0) { ss[wid] = sacc; qq[wid] = qacc; }
    __syncthreads();
    if (t == 0) {
        float s = 0.f, q = 0.f;
#pragma unroll
        for (int i = 0; i < 8; i++) { s += ss[i]; q += qq[i]; }
        part[b] = make_float2(s, q);
    }
}

// single-block reduction of per-block partials -> scal
__global__ __launch_bounds__(256) void k_statsred(const float2* __restrict__ part,
                                                  float* __restrict__ scal, int M) {
    int t = threadIdx.x;
    float s = 0.f, q = 0.f;
    for (int i = t; i < M; i += 256) {
        float2 v = part[i];
        s += v.x; q += v.y;
    }
    for (int off = 32; off > 0; off >>= 1) {
        s += __shfl_down(s, off, 64);
        q += __shfl_down(q, off, 64);
    }
    __shared__ float ss[4], qq[4];
    int lane = t & 63, wid = t >> 6;
    if (lane == 0) { ss[wid] = s; qq[wid] = q; }
    __syncthreads();
    if (t == 0) {
        scal[0] = ss[0] + ss[1] + ss[2] + ss[3];
        scal[1] = qq[0] + qq[1] + qq[2] + qq[3];
    }
}

// per batch rows: LN + PReLU on 16 channels, then x trans[16,128] -> out[B,128].
// 8 rows/block; tl column hoisted to registers.
__global__ __launch_bounds__(256) void k_final(const float* __restrict__ agg,
                                               const int* __restrict__ batch,
                                               const float* __restrict__ trans,
                                               const float* __restrict__ bias,
                                               const float* __restrict__ ln_w,
                                               const float* __restrict__ ln_b,
                                               const float* __restrict__ prelu_a,
                                               const float* __restrict__ scal,
                                               float* __restrict__ out, int B, float invCnt) {
    __shared__ float tl[16 * 128];
    __shared__ float hh[8 * 16];
    const int tid = threadIdx.x;
    for (int i = tid; i < 2048; i += 256) tl[i] = trans[i];
    float mean = scal[0] * invCnt;
    float var  = scal[1] * invCnt - mean * mean;
    float inv  = rsqrtf(var + EPS);
    int row0 = blockIdx.x * 8;
    if (tid < 128) {
        int lr = tid >> 4, r = tid & 15;
        int row = row0 + lr;
        if (row < B) {
            int node = batch[row];
            float v = agg[(size_t)node * 16 + r] + bias[r];
            v = (v - mean) * inv * ln_w[r] + ln_b[r];
            float a = prelu_a[0];
            v = v >= 0.f ? v : a * v;
            hh[lr * 16 + r] = v;
        }
    }
    __syncthreads();
    int d = tid & 127, hlf = tid >> 7;
    float tv[16];
#pragma unroll
    for (int r = 0; r < 16; r++) tv[r] = tl[r * 128 + d];
#pragma unroll
    for (int rr = 0; rr < 4; rr++) {
        int lr = rr * 2 + hlf;
        int row = row0 + lr;
        if (row < B) {
            const float* hrow = hh + lr * 16;
            float acc = 0.f;
#pragma unroll
            for (int r = 0; r < 16; r++) acc += hrow[r] * tv[r];
            out[(size_t)row * 128 + d] = acc;
        }
    }
}

extern "C" void kernel_launch(void* const* d_in, const int* in_sizes, int n_in,
                              void* d_out, int out_size, void* d_ws, size_t ws_size,
                              hipStream_t stream) {
    const float* x       = (const float*)d_in[0];
    const int*   ei      = (const int*)d_in[1];
    const float* trans   = (const float*)d_in[2];
    const int*   batch   = (const int*)d_in[3];
    const float* W       = (const float*)d_in[4];
    const float* bias    = (const float*)d_in[5];
    const float* ln_w    = (const float*)d_in[6];
    const float* ln_b    = (const float*)d_in[7];
    const float* prelu_a = (const float*)d_in[8];
    float* out = (float*)d_out;

    const int N = in_sizes[0] / 256;   // 100000
    const int E = in_sizes[1] / 2;     // 3200000
    const int B = in_sizes[3];         // 16384
    const int NB = (N + BSIZE - 1) >> BSHIFT;   // 391
    const int pbp = (E + PCHUNK - 1) / PCHUNK;  // 391 chunks
    const int NT = (N + 15) / 16;      // 6250 gemm wave-tiles

    char* p = (char*)d_ws;
    unsigned short* hs = (unsigned short*)p;  p += (size_t)N * 16 * 2;    // 3.2MB bf16
    float*    agg     = (float*)p;     p += (size_t)N * 16 * 4;           // 6.4MB
    unsigned* sorted  = (unsigned*)p;  p += (size_t)E * 4;                // 12.8MB
    unsigned* scratch = (unsigned*)p;  p += (size_t)E * 4;                // 12.8MB (fallback only)
    unsigned* blkhist = (unsigned*)p;  p += (size_t)pbp * NBMAX * 4;      // 800KB
    float*    dinv    = (float*)p;     p += (size_t)N * 4;
    unsigned* nstart  = (unsigned*)p;  p += (size_t)(N + 1) * 4;
    unsigned* ghist   = (unsigned*)p;  p += NBMAX * 4;
    unsigned* base    = (unsigned*)p;  p += (NBMAX + 1) * 4;
    unsigned* cursor  = (unsigned*)p;  p += NBMAX * 4;
    float*    scal    = (float*)p;     p += 2 * 4;
    p = (char*)(((size_t)p + 7) & ~(size_t)7);
    float2*   part    = (float2*)p;    p += (size_t)NB * 8;

    hipLaunchKernelGGL(k_zero,     dim3(1),               dim3(512), 0, stream, ghist, NB);
    hipLaunchKernelGGL(k_bhist,    dim3(pbp),             dim3(512), 0, stream, ei, ghist, blkhist, E, NB);
    hipLaunchKernelGGL(k_bscan,    dim3(1),               dim3(512), 0, stream, ghist, base, cursor, nstart, NB, N, E);
    hipLaunchKernelGGL(k_bpart,    dim3(pbp),             dim3(512), 0, stream, ei, blkhist, cursor, sorted, E, NB);
    hipLaunchKernelGGL(k_bdeg2,    dim3(NB),              dim3(512), 0, stream, base, sorted, nstart, dinv, N);
    hipLaunchKernelGGL(k_gemm,     dim3(512),             dim3(256), 0, stream, x, W, dinv, hs, N, NT);
    hipLaunchKernelGGL(k_aggf,     dim3(NB),              dim3(512), 0, stream, base, nstart, sorted, hs, dinv, bias, agg, part, scratch, N);
    hipLaunchKernelGGL(k_statsred, dim3(1),               dim3(256), 0, stream, part, scal, NB);
    hipLaunchKernelGGL(k_final,    dim3((B + 7) / 8),     dim3(256), 0, stream, agg, batch, trans, bias,
                       ln_w, ln_b, prelu_a, scal, out, B, 1.0f / (float)(N * 16));
}